// Round 13
// baseline (202.373 us; speedup 1.0000x reference)
//
#include <hip/hip_runtime.h>
#include <stdint.h>

typedef unsigned short u16;
typedef uint32_t u32;
typedef __attribute__((ext_vector_type(4))) float f32x4;
typedef __attribute__((ext_vector_type(16))) float f32x16;
typedef __attribute__((ext_vector_type(8))) short bf16x8;
typedef __attribute__((ext_vector_type(4))) u32 u32x4;

#define MFMA16(a,b,c) __builtin_amdgcn_mfma_f32_16x16x32_bf16((a),(b),(c),0,0,0)
#define MFMA32(a,b,c) __builtin_amdgcn_mfma_f32_32x32x16_bf16((a),(b),(c),0,0,0)
#define QSCALE 0.18033688011112042f   /* 0.125 * log2(e) */
#define MASKB  -1803.3688011112042f   /* -10000 * QSCALE */
#define MBASE  -16.0f                 /* fixed softmax base (log2 domain) */

__device__ __forceinline__ u16 f2bf(float f){
  union { float f; uint32_t u; } v; v.f = f;
  uint32_t r = v.u + 0x7fffu + ((v.u >> 16) & 1u);
  return (u16)(r >> 16);
}

__device__ __forceinline__ u32 cvtpk(float lo, float hi){
  u32 r;
  asm volatile("v_cvt_pk_bf16_f32 %0, %1, %2" : "=v"(r) : "v"(lo), "v"(hi));
  return r;
}

__device__ __forceinline__ void plswap(u32 &a, u32 &b){
  auto r = __builtin_amdgcn_permlane32_swap(a, b, false, false);
  union { decltype(r) v; u32 w[2]; } u; u.v = r;
  a = u.w[0]; b = u.w[1];
}

union U4 { u32x4 u; bf16x8 b; };
__device__ __forceinline__ bf16x8 mkfrag(u32 a, u32 b, u32 c, u32 d){
  U4 x; x.u = (u32x4){a,b,c,d}; return x.b;
}

__device__ __forceinline__ void gload16(const void* g, void* l){
  __builtin_amdgcn_global_load_lds(
      (const __attribute__((address_space(1))) void*)g,
      (__attribute__((address_space(3))) void*)l, 16, 0, 0);
}

// ---------------- fused pre-pass: cvt x + transpose w_qkv + transpose w_out ----------------
__global__ __launch_bounds__(256) void prep_k(const float* __restrict__ x, u16* __restrict__ xb,
                                              const float* __restrict__ w_qkv, u16* __restrict__ wqkvT,
                                              const float* __restrict__ w_out, u16* __restrict__ woutT){
  __shared__ float tile[64][65];
  const int id = blockIdx.x, t = threadIdx.x;
  if (id < 8192){
    int i = id*256 + t;
    float4 v = reinterpret_cast<const float4*>(x)[i];
    ushort4 o;
    o.x = f2bf(v.x); o.y = f2bf(v.y); o.z = f2bf(v.z); o.w = f2bf(v.w);
    reinterpret_cast<ushort4*>(xb)[i] = o;
    return;
  }
  const float* in; u16* out; int R, C, bx, by;
  if (id < 8960){ int id2 = id - 8192; in = w_qkv; out = wqkvT; R = 1024; C = 3072; bx = id2 % 48; by = id2 / 48; }
  else          { int id3 = id - 8960; in = w_out; out = woutT; R = 1024; C = 1024; bx = id3 % 16; by = id3 / 16; }
  int c0 = bx*64, r0 = by*64;
  int cc = t & 63, rr = t >> 6;
  #pragma unroll
  for (int i=0;i<16;++i){ int r = rr + i*4; tile[r][cc] = in[(size_t)(r0+r)*C + c0+cc]; }
  __syncthreads();
  #pragma unroll
  for (int i=0;i<16;++i){ int r = rr + i*4; out[(size_t)(c0+r)*R + r0+cc] = f2bf(tile[cc][r]); }
}

// ---------------- GEMM core (R4-proven): 128x128 tile, BK=64, 2-barrier ----------------
__device__ __forceinline__ void gemm_core(const u16* __restrict__ A, const u16* __restrict__ Bt,
                                          int bm, int bn, char* lds, f32x4 (&acc)[4][4]){
  const int K = 1024;
  int tid = threadIdx.x, w = tid >> 6, l = tid & 63;
  int lrow = l & 15, lg = l >> 4;
  int wm = w >> 1, wn = w & 1;
  const u16* aSrc = A + (size_t)(bm*128 + w*32 + (l>>3))*K + (((l&7)^(l>>3))<<3);
  const u16* bSrc = Bt + (size_t)(bn*128 + w*32 + (l>>3))*K + (((l&7)^(l>>3))<<3);
  char* aDst = lds + w*4096;
  char* bDst = lds + 16384 + w*4096;
  for (int kk = 0; kk < 16; ++kk){
    __syncthreads();
    #pragma unroll
    for (int i=0;i<4;++i) gload16(aSrc + (size_t)i*8*K + kk*64, aDst + i*1024);
    #pragma unroll
    for (int i=0;i<4;++i) gload16(bSrc + (size_t)i*8*K + kk*64, bDst + i*1024);
    __syncthreads();
    #pragma unroll
    for (int ks=0; ks<2; ++ks){
      bf16x8 af[4], bfv[4];
      #pragma unroll
      for (int m=0;m<4;++m){
        int row = wm*64 + m*16 + lrow;
        af[m] = *reinterpret_cast<const bf16x8*>(lds + row*128 + (((ks*4+lg)^(row&7))<<4));
      }
      #pragma unroll
      for (int n=0;n<4;++n){
        int row = wn*64 + n*16 + lrow;
        bfv[n] = *reinterpret_cast<const bf16x8*>(lds + 16384 + row*128 + (((ks*4+lg)^(row&7))<<4));
      }
      #pragma unroll
      for (int m=0;m<4;++m){
        #pragma unroll
        for (int n=0;n<4;++n)
          acc[m][n] = MFMA16(af[m], bfv[n], acc[m][n]);
      }
    }
  }
}

// ---------------- GEMM1: x @ w_qkvT^T -> NT-scatter q,k + LDS-transposed NT vT ----------------
__global__ __launch_bounds__(256,5) void gemm_qkv_k(const u16* __restrict__ A, const u16* __restrict__ Bt,
                                                    u16* __restrict__ qw, u16* __restrict__ kw,
                                                    u16* __restrict__ vtw){
  __shared__ __align__(16) char lds[32768];
  f32x4 acc[4][4];
  #pragma unroll
  for (int m=0;m<4;++m){
    #pragma unroll
    for (int n=0;n<4;++n) acc[m][n] = (f32x4){0.f,0.f,0.f,0.f};
  }
  int id = blockIdx.x + 24*blockIdx.y;  // 0..1535
  int xcd = id & 7, s = id >> 3;        // s: 0..191
  int cb = s / 48, r = s % 48;          // 4 column-passes of 8bm x 6bn
  int bm = xcd*8 + r/6;                 // 0..63
  int bn = cb*6 + r%6;                  // 0..23
  gemm_core(A, Bt, bm, bn, lds, acc);
  int tid = threadIdx.x, w = tid >> 6, l = tid & 63;
  int lrow = l & 15, lg = l >> 4;
  int wm = w >> 1, wn = w & 1;
  const int which = bn >> 3;   // 128-col block lies entirely in one of q/k/v
  if (which < 2){
    #pragma unroll
    for (int n=0;n<4;++n){
      int gcol = bn*128 + wn*64 + n*16 + lrow;
      int inner = gcol & 1023;
      int h = inner >> 6, d = inner & 63;
      #pragma unroll
      for (int m=0;m<4;++m){
        #pragma unroll
        for (int r2=0;r2<4;++r2){
          int grow = bm*128 + wm*64 + m*16 + lg*4 + r2; // b*S + s
          int b = grow >> 11, sq = grow & 2047;
          float v = acc[m][n][r2];
          u16 o = (which == 0) ? f2bf(v * QSCALE) : f2bf(v);
          u16* dst = (which == 0) ? qw : kw;
          __builtin_nontemporal_store(o, dst + ((size_t)((b*16 + h)*2048 + sq))*64 + d);
        }
      }
    }
  } else {
    // V block: transpose through LDS -> coalesced NT 16B stores to vtw[bh][d][sq]
    __syncthreads();
    #pragma unroll
    for (int n=0;n<4;++n){
      int colL = wn*64 + n*16 + lrow;           // local d' 0..127
      int swz = (colL & 7) << 4;
      #pragma unroll
      for (int m=0;m<4;++m){
        int rowL0 = wm*64 + m*16 + lg*4;        // local sq' 4 consecutive
        ushort4 p;
        p.x = f2bf(acc[m][n][0]); p.y = f2bf(acc[m][n][1]);
        p.z = f2bf(acc[m][n][2]); p.w = f2bf(acc[m][n][3]);
        *reinterpret_cast<ushort4*>(lds + colL*256 + ((rowL0*2) ^ swz)) = p;
      }
    }
    __syncthreads();
    const int h0 = bn*2 - 32;
    const int grow0 = bm*128;
    const int b = grow0 >> 11, sq0 = grow0 & 2047;
    const int dp = tid >> 1;
    const int half = (tid & 1) * 128;
    const int h = h0 + (dp >> 6), d = dp & 63;
    const int swz = (dp & 7) << 4;
    u16* dst = vtw + ((size_t)((b*16 + h)*64 + d))*2048 + sq0 + half/2;
    #pragma unroll
    for (int i=0;i<8;++i){
      u32x4 v = *reinterpret_cast<const u32x4*>(lds + dp*256 + ((half + i*16) ^ swz));
      __builtin_nontemporal_store(v, reinterpret_cast<u32x4*>(dst + i*8));
    }
  }
}

// ---------------- flash attention v5 (R9-proven): fixed-base softmax, l-sum via MFMA ----------------
__global__ __launch_bounds__(256) void attn_k(const u16* __restrict__ Qw, const u16* __restrict__ Kw,
                                              const u16* __restrict__ VTw, u16* __restrict__ Ow){
  __shared__ __align__(16) char lds[32768];
  const int bh = blockIdx.x;
  const int y = blockIdx.y, yk = y >> 2, ya = y & 3;
  const int qb = (yk == 0) ? (15 - ya) : (yk == 1) ? (8 + ya) : (yk == 2) ? (4 + ya) : (3 - ya);
  const int tid = threadIdx.x, w = tid >> 6, l = tid & 63;
  const int lo = l & 31, hi = l >> 5;
  const size_t base = (size_t)bh * (2048*64);
  const int qw0 = qb*128 + w*32;
  const int q_l = qw0 + lo;

  bf16x8 qa[4];
  {
    const u16* qsrc = Qw + base + (size_t)q_l*64 + hi*8;
    #pragma unroll
    for (int ks=0; ks<4; ++ks) qa[ks] = *reinterpret_cast<const bf16x8*>(qsrc + ks*16);
  }

  const u32 ONE2 = 0x3F803F80u;
  const bf16x8 onesf = mkfrag(ONE2, ONE2, ONE2, ONE2);

  const int srow = tid >> 3;
  const int scs  = (tid & 7) ^ (srow & 7);
  const u16* kS = Kw  + base + (size_t)srow*64   + scs*8;
  const u16* vS = VTw + base + (size_t)srow*2048 + scs*8;

  f32x16 acc0 = {0,0,0,0,0,0,0,0,0,0,0,0,0,0,0,0};
  f32x16 acc1 = {0,0,0,0,0,0,0,0,0,0,0,0,0,0,0,0};
  f32x16 ls   = {0,0,0,0,0,0,0,0,0,0,0,0,0,0,0,0};
  const f32x16 minit = {MBASE,MBASE,MBASE,MBASE,MBASE,MBASE,MBASE,MBASE,
                        MBASE,MBASE,MBASE,MBASE,MBASE,MBASE,MBASE,MBASE};

  const int nt = qb*2 + 2;

  #define STAGE(buf, t) do { \
    int kv0_ = (t)*64; \
    gload16(kS + (size_t)kv0_*64,        lds + (buf)*16384 +     0 + w*1024); \
    gload16(kS + (size_t)(kv0_+32)*64,   lds + (buf)*16384 +  4096 + w*1024); \
    gload16(vS + kv0_,                   lds + (buf)*16384 +  8192 + w*1024); \
    gload16(vS + kv0_ + (size_t)32*2048, lds + (buf)*16384 + 12288 + w*1024); \
  } while(0)

  STAGE(0, 0);
  __syncthreads();

  int cur = 0;
  for (int t = 0; t < nt; ++t){
    if (t+1 < nt){
      if (cur) STAGE(0, t+1); else STAGE(1, t+1);
    }
    const int kv0 = t*64;
    const char* KB = lds + cur*16384;
    const char* VB = KB + 8192;
    if (kv0 + 63 <= qw0){
      f32x16 s0 = minit;
      f32x16 s1 = minit;
      __builtin_amdgcn_s_setprio(1);
      #pragma unroll
      for (int ks=0; ks<4; ++ks){
        int kr0 = lo, kr1 = 32 + lo;
        bf16x8 kf0 = *reinterpret_cast<const bf16x8*>(KB + kr0*128 + ((ks*32 + hi*16) ^ ((kr0&7)<<4)));
        bf16x8 kf1 = *reinterpret_cast<const bf16x8*>(KB + kr1*128 + ((ks*32 + hi*16) ^ ((kr1&7)<<4)));
        s0 = MFMA32(kf0, qa[ks], s0);
        s1 = MFMA32(kf1, qa[ks], s1);
      }
      __builtin_amdgcn_s_setprio(0);
      #pragma unroll
      for (int r=0; r<16; ++r) s0[r] = exp2f(s0[r]);
      #pragma unroll
      for (int r=0; r<16; ++r) s1[r] = exp2f(s1[r]);
      u32 wd0 = cvtpk(s0[0],s0[1]),   wd1 = cvtpk(s0[2],s0[3]);
      u32 wd2 = cvtpk(s0[4],s0[5]),   wd3 = cvtpk(s0[6],s0[7]);
      u32 wd4 = cvtpk(s0[8],s0[9]),   wd5 = cvtpk(s0[10],s0[11]);
      u32 wd6 = cvtpk(s0[12],s0[13]), wd7 = cvtpk(s0[14],s0[15]);
      u32 we0 = cvtpk(s1[0],s1[1]),   we1 = cvtpk(s1[2],s1[3]);
      u32 we2 = cvtpk(s1[4],s1[5]),   we3 = cvtpk(s1[6],s1[7]);
      u32 we4 = cvtpk(s1[8],s1[9]),   we5 = cvtpk(s1[10],s1[11]);
      u32 we6 = cvtpk(s1[12],s1[13]), we7 = cvtpk(s1[14],s1[15]);
      plswap(wd0, wd2); plswap(wd1, wd3); plswap(wd4, wd6); plswap(wd5, wd7);
      plswap(we0, we2); plswap(we1, we3); plswap(we4, we6); plswap(we5, we7);
      bf16x8 pf0 = mkfrag(wd0, wd1, wd2, wd3);
      bf16x8 pf1 = mkfrag(wd4, wd5, wd6, wd7);
      bf16x8 pf2 = mkfrag(we0, we1, we2, we3);
      bf16x8 pf3 = mkfrag(we4, we5, we6, we7);
      __builtin_amdgcn_s_setprio(1);
      {
        int vrow = lo;
        bf16x8 v0 = *reinterpret_cast<const bf16x8*>(VB + vrow*128 + ((      hi*16) ^ ((vrow&7)<<4)));
        bf16x8 v1 = *reinterpret_cast<const bf16x8*>(VB + vrow*128 + (( 32 + hi*16) ^ ((vrow&7)<<4)));
        bf16x8 v2 = *reinterpret_cast<const bf16x8*>(VB + vrow*128 + (( 64 + hi*16) ^ ((vrow&7)<<4)));
        bf16x8 v3 = *reinterpret_cast<const bf16x8*>(VB + vrow*128 + (( 96 + hi*16) ^ ((vrow&7)<<4)));
        acc0 = MFMA32(v0, pf0, acc0);
        acc0 = MFMA32(v1, pf1, acc0);
        acc0 = MFMA32(v2, pf2, acc0);
        acc0 = MFMA32(v3, pf3, acc0);
      }
      {
        int vrow = 32 + lo;
        bf16x8 v0 = *reinterpret_cast<const bf16x8*>(VB + vrow*128 + ((      hi*16) ^ ((vrow&7)<<4)));
        bf16x8 v1 = *reinterpret_cast<const bf16x8*>(VB + vrow*128 + (( 32 + hi*16) ^ ((vrow&7)<<4)));
        bf16x8 v2 = *reinterpret_cast<const bf16x8*>(VB + vrow*128 + (( 64 + hi*16) ^ ((vrow&7)<<4)));
        bf16x8 v3 = *reinterpret_cast<const bf16x8*>(VB + vrow*128 + (( 96 + hi*16) ^ ((vrow&7)<<4)));
        acc1 = MFMA32(v0, pf0, acc1);
        acc1 = MFMA32(v1, pf1, acc1);
        acc1 = MFMA32(v2, pf2, acc1);
        acc1 = MFMA32(v3, pf3, acc1);
      }
      ls = MFMA32(onesf, pf0, ls);
      ls = MFMA32(onesf, pf1, ls);
      ls = MFMA32(onesf, pf2, ls);
      ls = MFMA32(onesf, pf3, ls);
      __builtin_amdgcn_s_setprio(0);
    } else if (kv0 < qw0 + 32){
      #pragma unroll
      for (int t2=0; t2<2; ++t2){
        const int kvs0 = kv0 + t2*32;
        if (kvs0 < qw0 + 32){
          f32x16 s = minit;
          __builtin_amdgcn_s_setprio(1);
          #pragma unroll
          for (int ks=0; ks<4; ++ks){
            int krow = t2*32 + lo;
            bf16x8 kf = *reinterpret_cast<const bf16x8*>(KB + krow*128 + ((ks*32 + hi*16) ^ ((krow&7)<<4)));
            s = MFMA32(kf, qa[ks], s);
          }
          __builtin_amdgcn_s_setprio(0);
          if (kvs0 + 31 > qw0){
            #pragma unroll
            for (int r=0; r<16; ++r){
              int kvg = kvs0 + (r&3) + 8*(r>>2) + 4*hi;
              if (kvg > q_l) s[r] += MASKB;
            }
          }
          #pragma unroll
          for (int r=0; r<16; ++r) s[r] = exp2f(s[r]);
          u32 wd0 = cvtpk(s[0], s[1]),   wd1 = cvtpk(s[2], s[3]);
          u32 wd2 = cvtpk(s[4], s[5]),   wd3 = cvtpk(s[6], s[7]);
          u32 wd4 = cvtpk(s[8], s[9]),   wd5 = cvtpk(s[10], s[11]);
          u32 wd6 = cvtpk(s[12], s[13]), wd7 = cvtpk(s[14], s[15]);
          plswap(wd0, wd2); plswap(wd1, wd3);
          plswap(wd4, wd6); plswap(wd5, wd7);
          bf16x8 pf0 = mkfrag(wd0, wd1, wd2, wd3);
          bf16x8 pf1 = mkfrag(wd4, wd5, wd6, wd7);
          __builtin_amdgcn_s_setprio(1);
          {
            int vrow = lo;
            bf16x8 v0 = *reinterpret_cast<const bf16x8*>(VB + vrow*128 + ((t2*64 +      hi*16) ^ ((vrow&7)<<4)));
            bf16x8 v1 = *reinterpret_cast<const bf16x8*>(VB + vrow*128 + ((t2*64 + 32 + hi*16) ^ ((vrow&7)<<4)));
            acc0 = MFMA32(v0, pf0, acc0);
            acc0 = MFMA32(v1, pf1, acc0);
          }
          {
            int vrow = 32 + lo;
            bf16x8 v0 = *reinterpret_cast<const bf16x8*>(VB + vrow*128 + ((t2*64 +      hi*16) ^ ((vrow&7)<<4)));
            bf16x8 v1 = *reinterpret_cast<const bf16x8*>(VB + vrow*128 + ((t2*64 + 32 + hi*16) ^ ((vrow&7)<<4)));
            acc1 = MFMA32(v0, pf0, acc1);
            acc1 = MFMA32(v1, pf1, acc1);
          }
          ls = MFMA32(onesf, pf0, ls);
          ls = MFMA32(onesf, pf1, ls);
          __builtin_amdgcn_s_setprio(0);
        }
      }
    }
    __syncthreads();
    cur ^= 1;
  }
  #undef STAGE

  char* T = lds + w*4096;
  float inv = 1.0f / ls[0];
  #pragma unroll
  for (int i=0; i<8; ++i){
    int d = (2*i & 3) + 8*(2*i >> 2) + 4*hi;
    u32 wv0 = cvtpk(acc0[2*i]*inv, acc0[2*i+1]*inv);
    *reinterpret_cast<u32*>(T + lo*128 + ((d*2) ^ ((lo&7)<<4))) = wv0;
    u32 wv1 = cvtpk(acc1[2*i]*inv, acc1[2*i+1]*inv);
    *reinterpret_cast<u32*>(T + lo*128 + (((d+32)*2) ^ ((lo&7)<<4))) = wv1;
  }
  __syncthreads();
  const int b = bh >> 4, h = bh & 15;
  #pragma unroll
  for (int i=0; i<4; ++i){
    int q = i*8 + (l>>3), slot = l&7;
    bf16x8 v = *reinterpret_cast<const bf16x8*>(T + q*128 + ((slot*16) ^ ((q&7)<<4)));
    int sq = qb*128 + w*32 + q;
    *reinterpret_cast<bf16x8*>(Ow + ((size_t)(b*2048 + sq))*1024 + h*64 + slot*8) = v;
  }
}

// ---------------- GEMM2: attn @ w_outT^T + bias -> NT f32 out ----------------
__global__ __launch_bounds__(256,4) void gemm_out_k(const u16* __restrict__ A, const u16* __restrict__ Bt,
                                                    const float* __restrict__ bias_p, float* __restrict__ out){
  __shared__ __align__(16) char lds[32768];
  f32x4 acc[4][4];
  #pragma unroll
  for (int m=0;m<4;++m){
    #pragma unroll
    for (int n=0;n<4;++n) acc[m][n] = (f32x4){0.f,0.f,0.f,0.f};
  }
  int id = blockIdx.x + 8*blockIdx.y;
  int nid = (id & 7)*64 + (id >> 3);
  int bn = nid % 8, bm = nid / 8;
  gemm_core(A, Bt, bm, bn, lds, acc);
  int tid = threadIdx.x, w = tid >> 6, l = tid & 63;
  int lrow = l & 15, lg = l >> 4;
  int wm = w >> 1, wn = w & 1;
  #pragma unroll
  for (int n=0;n<4;++n){
    int gcol = bn*128 + wn*64 + n*16 + lrow;
    float bias = bias_p[gcol];
    #pragma unroll
    for (int m=0;m<4;++m){
      #pragma unroll
      for (int r=0;r<4;++r){
        int grow = bm*128 + wm*64 + m*16 + lg*4 + r;
        __builtin_nontemporal_store(acc[m][n][r] + bias, out + (size_t)grow*1024 + gcol);
      }
    }
  }
}

extern "C" void kernel_launch(void* const* d_in, const int* in_sizes, int n_in,
                              void* d_out, int out_size, void* d_ws, size_t ws_size,
                              hipStream_t stream){
  (void)in_sizes; (void)n_in; (void)out_size; (void)ws_size;
  const float* x     = (const float*)d_in[0];
  const float* w_qkv = (const float*)d_in[1];
  const float* w_out = (const float*)d_in[2];
  const float* b_out = (const float*)d_in[3];
  float* out = (float*)d_out;
  char* ws = (char*)d_ws;
  u16* xb    = (u16*)(ws + 0);
  u16* wqkvT = (u16*)(ws + 16777216);
  u16* woutT = (u16*)(ws + 23068672);
  u16* qw    = (u16*)(ws + 25165824);
  u16* kw    = (u16*)(ws + 41943040);
  u16* vtw   = (u16*)(ws + 58720256);
  u16* attn  = (u16*)(ws + 75497472);

  prep_k<<<9216, 256, 0, stream>>>(x, xb, w_qkv, wqkvT, w_out, woutT);
  gemm_qkv_k<<<dim3(24,64), 256, 0, stream>>>(xb, wqkvT, qw, kw, vtw);
  attn_k<<<dim3(64,16), 256, 0, stream>>>(qw, kw, vtw, attn);
  gemm_out_k<<<dim3(8,64), 256, 0, stream>>>(attn, woutT, b_out, out);
}

// Round 14
// 184.597 us; speedup vs baseline: 1.0963x; 1.0963x over previous
//
#include <hip/hip_runtime.h>
#include <stdint.h>

typedef unsigned short u16;
typedef uint32_t u32;
typedef __attribute__((ext_vector_type(4))) float f32x4;
typedef __attribute__((ext_vector_type(16))) float f32x16;
typedef __attribute__((ext_vector_type(8))) short bf16x8;
typedef __attribute__((ext_vector_type(4))) u32 u32x4;

#define MFMA16(a,b,c) __builtin_amdgcn_mfma_f32_16x16x32_bf16((a),(b),(c),0,0,0)
#define MFMA32(a,b,c) __builtin_amdgcn_mfma_f32_32x32x16_bf16((a),(b),(c),0,0,0)
#define QSCALE 0.18033688011112042f   /* 0.125 * log2(e) */
#define MASKB  -1803.3688011112042f   /* -10000 * QSCALE */
#define MBASE  -16.0f                 /* fixed softmax base (log2 domain) */

__device__ __forceinline__ u16 f2bf(float f){
  union { float f; uint32_t u; } v; v.f = f;
  uint32_t r = v.u + 0x7fffu + ((v.u >> 16) & 1u);
  return (u16)(r >> 16);
}

__device__ __forceinline__ u32 cvtpk(float lo, float hi){
  u32 r;
  asm volatile("v_cvt_pk_bf16_f32 %0, %1, %2" : "=v"(r) : "v"(lo), "v"(hi));
  return r;
}

__device__ __forceinline__ void plswap(u32 &a, u32 &b){
  auto r = __builtin_amdgcn_permlane32_swap(a, b, false, false);
  union { decltype(r) v; u32 w[2]; } u; u.v = r;
  a = u.w[0]; b = u.w[1];
}

union U4 { u32x4 u; bf16x8 b; };
__device__ __forceinline__ bf16x8 mkfrag(u32 a, u32 b, u32 c, u32 d){
  U4 x; x.u = (u32x4){a,b,c,d}; return x.b;
}

__device__ __forceinline__ void gload16(const void* g, void* l){
  __builtin_amdgcn_global_load_lds(
      (const __attribute__((address_space(1))) void*)g,
      (__attribute__((address_space(3))) void*)l, 16, 0, 0);
}

// ---------------- fused pre-pass: cvt x + transpose w_qkv + transpose w_out ----------------
__global__ __launch_bounds__(256) void prep_k(const float* __restrict__ x, u16* __restrict__ xb,
                                              const float* __restrict__ w_qkv, u16* __restrict__ wqkvT,
                                              const float* __restrict__ w_out, u16* __restrict__ woutT){
  __shared__ float tile[64][65];
  const int id = blockIdx.x, t = threadIdx.x;
  if (id < 8192){
    int i = id*256 + t;
    float4 v = reinterpret_cast<const float4*>(x)[i];
    ushort4 o;
    o.x = f2bf(v.x); o.y = f2bf(v.y); o.z = f2bf(v.z); o.w = f2bf(v.w);
    reinterpret_cast<ushort4*>(xb)[i] = o;
    return;
  }
  const float* in; u16* out; int R, C, bx, by;
  if (id < 8960){ int id2 = id - 8192; in = w_qkv; out = wqkvT; R = 1024; C = 3072; bx = id2 % 48; by = id2 / 48; }
  else          { int id3 = id - 8960; in = w_out; out = woutT; R = 1024; C = 1024; bx = id3 % 16; by = id3 / 16; }
  int c0 = bx*64, r0 = by*64;
  int cc = t & 63, rr = t >> 6;
  #pragma unroll
  for (int i=0;i<16;++i){ int r = rr + i*4; tile[r][cc] = in[(size_t)(r0+r)*C + c0+cc]; }
  __syncthreads();
  #pragma unroll
  for (int i=0;i<16;++i){ int r = rr + i*4; out[(size_t)(c0+r)*R + r0+cc] = f2bf(tile[cc][r]); }
}

// ---------------- GEMM core (R4-proven): 128x128 tile, BK=64, 2-barrier ----------------
__device__ __forceinline__ void gemm_core(const u16* __restrict__ A, const u16* __restrict__ Bt,
                                          int bm, int bn, char* lds, f32x4 (&acc)[4][4]){
  const int K = 1024;
  int tid = threadIdx.x, w = tid >> 6, l = tid & 63;
  int lrow = l & 15, lg = l >> 4;
  int wm = w >> 1, wn = w & 1;
  const u16* aSrc = A + (size_t)(bm*128 + w*32 + (l>>3))*K + (((l&7)^(l>>3))<<3);
  const u16* bSrc = Bt + (size_t)(bn*128 + w*32 + (l>>3))*K + (((l&7)^(l>>3))<<3);
  char* aDst = lds + w*4096;
  char* bDst = lds + 16384 + w*4096;
  for (int kk = 0; kk < 16; ++kk){
    __syncthreads();
    #pragma unroll
    for (int i=0;i<4;++i) gload16(aSrc + (size_t)i*8*K + kk*64, aDst + i*1024);
    #pragma unroll
    for (int i=0;i<4;++i) gload16(bSrc + (size_t)i*8*K + kk*64, bDst + i*1024);
    __syncthreads();
    #pragma unroll
    for (int ks=0; ks<2; ++ks){
      bf16x8 af[4], bfv[4];
      #pragma unroll
      for (int m=0;m<4;++m){
        int row = wm*64 + m*16 + lrow;
        af[m] = *reinterpret_cast<const bf16x8*>(lds + row*128 + (((ks*4+lg)^(row&7))<<4));
      }
      #pragma unroll
      for (int n=0;n<4;++n){
        int row = wn*64 + n*16 + lrow;
        bfv[n] = *reinterpret_cast<const bf16x8*>(lds + 16384 + row*128 + (((ks*4+lg)^(row&7))<<4));
      }
      #pragma unroll
      for (int m=0;m<4;++m){
        #pragma unroll
        for (int n=0;n<4;++n)
          acc[m][n] = MFMA16(af[m], bfv[n], acc[m][n]);
      }
    }
  }
}

// ---------------- GEMM1: x @ w_qkvT^T -> cached scatter q,k + LDS-transposed NT vT ----------------
__global__ __launch_bounds__(256,5) void gemm_qkv_k(const u16* __restrict__ A, const u16* __restrict__ Bt,
                                                    u16* __restrict__ qw, u16* __restrict__ kw,
                                                    u16* __restrict__ vtw){
  __shared__ __align__(16) char lds[32768];
  f32x4 acc[4][4];
  #pragma unroll
  for (int m=0;m<4;++m){
    #pragma unroll
    for (int n=0;n<4;++n) acc[m][n] = (f32x4){0.f,0.f,0.f,0.f};
  }
  int id = blockIdx.x + 24*blockIdx.y;  // 0..1535
  int xcd = id & 7, s = id >> 3;        // s: 0..191
  int cb = s / 48, r = s % 48;          // 4 column-passes of 8bm x 6bn
  int bm = xcd*8 + r/6;                 // 0..63
  int bn = cb*6 + r%6;                  // 0..23
  gemm_core(A, Bt, bm, bn, lds, acc);
  int tid = threadIdx.x, w = tid >> 6, l = tid & 63;
  int lrow = l & 15, lg = l >> 4;
  int wm = w >> 1, wn = w & 1;
  const int which = bn >> 3;   // 128-col block lies entirely in one of q/k/v
  if (which < 2){
    // cached stores: L2 write-combines the 2B/lane scatter into full sectors (R13 lesson)
    #pragma unroll
    for (int n=0;n<4;++n){
      int gcol = bn*128 + wn*64 + n*16 + lrow;
      int inner = gcol & 1023;
      int h = inner >> 6, d = inner & 63;
      #pragma unroll
      for (int m=0;m<4;++m){
        #pragma unroll
        for (int r2=0;r2<4;++r2){
          int grow = bm*128 + wm*64 + m*16 + lg*4 + r2; // b*S + s
          int b = grow >> 11, sq = grow & 2047;
          float v = acc[m][n][r2];
          if (which == 0)
            qw[((size_t)((b*16 + h)*2048 + sq))*64 + d] = f2bf(v * QSCALE);
          else
            kw[((size_t)((b*16 + h)*2048 + sq))*64 + d] = f2bf(v);
        }
      }
    }
  } else {
    // V block: transpose through LDS -> coalesced NT 16B stores (full-line) to vtw[bh][d][sq]
    __syncthreads();
    #pragma unroll
    for (int n=0;n<4;++n){
      int colL = wn*64 + n*16 + lrow;           // local d' 0..127
      int swz = (colL & 7) << 4;
      #pragma unroll
      for (int m=0;m<4;++m){
        int rowL0 = wm*64 + m*16 + lg*4;        // local sq' 4 consecutive
        ushort4 p;
        p.x = f2bf(acc[m][n][0]); p.y = f2bf(acc[m][n][1]);
        p.z = f2bf(acc[m][n][2]); p.w = f2bf(acc[m][n][3]);
        *reinterpret_cast<ushort4*>(lds + colL*256 + ((rowL0*2) ^ swz)) = p;
      }
    }
    __syncthreads();
    const int h0 = bn*2 - 32;
    const int grow0 = bm*128;
    const int b = grow0 >> 11, sq0 = grow0 & 2047;
    const int dp = tid >> 1;
    const int half = (tid & 1) * 128;
    const int h = h0 + (dp >> 6), d = dp & 63;
    const int swz = (dp & 7) << 4;
    u16* dst = vtw + ((size_t)((b*16 + h)*64 + d))*2048 + sq0 + half/2;
    #pragma unroll
    for (int i=0;i<8;++i){
      u32x4 v = *reinterpret_cast<const u32x4*>(lds + dp*256 + ((half + i*16) ^ swz));
      __builtin_nontemporal_store(v, reinterpret_cast<u32x4*>(dst + i*8));
    }
  }
}

// ---------------- flash attention v5 (R9-proven): fixed-base softmax, l-sum via MFMA ----------------
__global__ __launch_bounds__(256) void attn_k(const u16* __restrict__ Qw, const u16* __restrict__ Kw,
                                              const u16* __restrict__ VTw, u16* __restrict__ Ow){
  __shared__ __align__(16) char lds[32768];
  const int bh = blockIdx.x;
  const int y = blockIdx.y, yk = y >> 2, ya = y & 3;
  const int qb = (yk == 0) ? (15 - ya) : (yk == 1) ? (8 + ya) : (yk == 2) ? (4 + ya) : (3 - ya);
  const int tid = threadIdx.x, w = tid >> 6, l = tid & 63;
  const int lo = l & 31, hi = l >> 5;
  const size_t base = (size_t)bh * (2048*64);
  const int qw0 = qb*128 + w*32;
  const int q_l = qw0 + lo;

  bf16x8 qa[4];
  {
    const u16* qsrc = Qw + base + (size_t)q_l*64 + hi*8;
    #pragma unroll
    for (int ks=0; ks<4; ++ks) qa[ks] = *reinterpret_cast<const bf16x8*>(qsrc + ks*16);
  }

  const u32 ONE2 = 0x3F803F80u;
  const bf16x8 onesf = mkfrag(ONE2, ONE2, ONE2, ONE2);

  const int srow = tid >> 3;
  const int scs  = (tid & 7) ^ (srow & 7);
  const u16* kS = Kw  + base + (size_t)srow*64   + scs*8;
  const u16* vS = VTw + base + (size_t)srow*2048 + scs*8;

  f32x16 acc0 = {0,0,0,0,0,0,0,0,0,0,0,0,0,0,0,0};
  f32x16 acc1 = {0,0,0,0,0,0,0,0,0,0,0,0,0,0,0,0};
  f32x16 ls   = {0,0,0,0,0,0,0,0,0,0,0,0,0,0,0,0};
  const f32x16 minit = {MBASE,MBASE,MBASE,MBASE,MBASE,MBASE,MBASE,MBASE,
                        MBASE,MBASE,MBASE,MBASE,MBASE,MBASE,MBASE,MBASE};

  const int nt = qb*2 + 2;

  #define STAGE(buf, t) do { \
    int kv0_ = (t)*64; \
    gload16(kS + (size_t)kv0_*64,        lds + (buf)*16384 +     0 + w*1024); \
    gload16(kS + (size_t)(kv0_+32)*64,   lds + (buf)*16384 +  4096 + w*1024); \
    gload16(vS + kv0_,                   lds + (buf)*16384 +  8192 + w*1024); \
    gload16(vS + kv0_ + (size_t)32*2048, lds + (buf)*16384 + 12288 + w*1024); \
  } while(0)

  STAGE(0, 0);
  __syncthreads();

  int cur = 0;
  for (int t = 0; t < nt; ++t){
    if (t+1 < nt){
      if (cur) STAGE(0, t+1); else STAGE(1, t+1);
    }
    const int kv0 = t*64;
    const char* KB = lds + cur*16384;
    const char* VB = KB + 8192;
    if (kv0 + 63 <= qw0){
      f32x16 s0 = minit;
      f32x16 s1 = minit;
      __builtin_amdgcn_s_setprio(1);
      #pragma unroll
      for (int ks=0; ks<4; ++ks){
        int kr0 = lo, kr1 = 32 + lo;
        bf16x8 kf0 = *reinterpret_cast<const bf16x8*>(KB + kr0*128 + ((ks*32 + hi*16) ^ ((kr0&7)<<4)));
        bf16x8 kf1 = *reinterpret_cast<const bf16x8*>(KB + kr1*128 + ((ks*32 + hi*16) ^ ((kr1&7)<<4)));
        s0 = MFMA32(kf0, qa[ks], s0);
        s1 = MFMA32(kf1, qa[ks], s1);
      }
      __builtin_amdgcn_s_setprio(0);
      #pragma unroll
      for (int r=0; r<16; ++r) s0[r] = exp2f(s0[r]);
      #pragma unroll
      for (int r=0; r<16; ++r) s1[r] = exp2f(s1[r]);
      u32 wd0 = cvtpk(s0[0],s0[1]),   wd1 = cvtpk(s0[2],s0[3]);
      u32 wd2 = cvtpk(s0[4],s0[5]),   wd3 = cvtpk(s0[6],s0[7]);
      u32 wd4 = cvtpk(s0[8],s0[9]),   wd5 = cvtpk(s0[10],s0[11]);
      u32 wd6 = cvtpk(s0[12],s0[13]), wd7 = cvtpk(s0[14],s0[15]);
      u32 we0 = cvtpk(s1[0],s1[1]),   we1 = cvtpk(s1[2],s1[3]);
      u32 we2 = cvtpk(s1[4],s1[5]),   we3 = cvtpk(s1[6],s1[7]);
      u32 we4 = cvtpk(s1[8],s1[9]),   we5 = cvtpk(s1[10],s1[11]);
      u32 we6 = cvtpk(s1[12],s1[13]), we7 = cvtpk(s1[14],s1[15]);
      plswap(wd0, wd2); plswap(wd1, wd3); plswap(wd4, wd6); plswap(wd5, wd7);
      plswap(we0, we2); plswap(we1, we3); plswap(we4, we6); plswap(we5, we7);
      bf16x8 pf0 = mkfrag(wd0, wd1, wd2, wd3);
      bf16x8 pf1 = mkfrag(wd4, wd5, wd6, wd7);
      bf16x8 pf2 = mkfrag(we0, we1, we2, we3);
      bf16x8 pf3 = mkfrag(we4, we5, we6, we7);
      __builtin_amdgcn_s_setprio(1);
      {
        int vrow = lo;
        bf16x8 v0 = *reinterpret_cast<const bf16x8*>(VB + vrow*128 + ((      hi*16) ^ ((vrow&7)<<4)));
        bf16x8 v1 = *reinterpret_cast<const bf16x8*>(VB + vrow*128 + (( 32 + hi*16) ^ ((vrow&7)<<4)));
        bf16x8 v2 = *reinterpret_cast<const bf16x8*>(VB + vrow*128 + (( 64 + hi*16) ^ ((vrow&7)<<4)));
        bf16x8 v3 = *reinterpret_cast<const bf16x8*>(VB + vrow*128 + (( 96 + hi*16) ^ ((vrow&7)<<4)));
        acc0 = MFMA32(v0, pf0, acc0);
        acc0 = MFMA32(v1, pf1, acc0);
        acc0 = MFMA32(v2, pf2, acc0);
        acc0 = MFMA32(v3, pf3, acc0);
      }
      {
        int vrow = 32 + lo;
        bf16x8 v0 = *reinterpret_cast<const bf16x8*>(VB + vrow*128 + ((      hi*16) ^ ((vrow&7)<<4)));
        bf16x8 v1 = *reinterpret_cast<const bf16x8*>(VB + vrow*128 + (( 32 + hi*16) ^ ((vrow&7)<<4)));
        bf16x8 v2 = *reinterpret_cast<const bf16x8*>(VB + vrow*128 + (( 64 + hi*16) ^ ((vrow&7)<<4)));
        bf16x8 v3 = *reinterpret_cast<const bf16x8*>(VB + vrow*128 + (( 96 + hi*16) ^ ((vrow&7)<<4)));
        acc1 = MFMA32(v0, pf0, acc1);
        acc1 = MFMA32(v1, pf1, acc1);
        acc1 = MFMA32(v2, pf2, acc1);
        acc1 = MFMA32(v3, pf3, acc1);
      }
      ls = MFMA32(onesf, pf0, ls);
      ls = MFMA32(onesf, pf1, ls);
      ls = MFMA32(onesf, pf2, ls);
      ls = MFMA32(onesf, pf3, ls);
      __builtin_amdgcn_s_setprio(0);
    } else if (kv0 < qw0 + 32){
      #pragma unroll
      for (int t2=0; t2<2; ++t2){
        const int kvs0 = kv0 + t2*32;
        if (kvs0 < qw0 + 32){
          f32x16 s = minit;
          __builtin_amdgcn_s_setprio(1);
          #pragma unroll
          for (int ks=0; ks<4; ++ks){
            int krow = t2*32 + lo;
            bf16x8 kf = *reinterpret_cast<const bf16x8*>(KB + krow*128 + ((ks*32 + hi*16) ^ ((krow&7)<<4)));
            s = MFMA32(kf, qa[ks], s);
          }
          __builtin_amdgcn_s_setprio(0);
          if (kvs0 + 31 > qw0){
            #pragma unroll
            for (int r=0; r<16; ++r){
              int kvg = kvs0 + (r&3) + 8*(r>>2) + 4*hi;
              if (kvg > q_l) s[r] += MASKB;
            }
          }
          #pragma unroll
          for (int r=0; r<16; ++r) s[r] = exp2f(s[r]);
          u32 wd0 = cvtpk(s[0], s[1]),   wd1 = cvtpk(s[2], s[3]);
          u32 wd2 = cvtpk(s[4], s[5]),   wd3 = cvtpk(s[6], s[7]);
          u32 wd4 = cvtpk(s[8], s[9]),   wd5 = cvtpk(s[10], s[11]);
          u32 wd6 = cvtpk(s[12], s[13]), wd7 = cvtpk(s[14], s[15]);
          plswap(wd0, wd2); plswap(wd1, wd3);
          plswap(wd4, wd6); plswap(wd5, wd7);
          bf16x8 pf0 = mkfrag(wd0, wd1, wd2, wd3);
          bf16x8 pf1 = mkfrag(wd4, wd5, wd6, wd7);
          __builtin_amdgcn_s_setprio(1);
          {
            int vrow = lo;
            bf16x8 v0 = *reinterpret_cast<const bf16x8*>(VB + vrow*128 + ((t2*64 +      hi*16) ^ ((vrow&7)<<4)));
            bf16x8 v1 = *reinterpret_cast<const bf16x8*>(VB + vrow*128 + ((t2*64 + 32 + hi*16) ^ ((vrow&7)<<4)));
            acc0 = MFMA32(v0, pf0, acc0);
            acc0 = MFMA32(v1, pf1, acc0);
          }
          {
            int vrow = 32 + lo;
            bf16x8 v0 = *reinterpret_cast<const bf16x8*>(VB + vrow*128 + ((t2*64 +      hi*16) ^ ((vrow&7)<<4)));
            bf16x8 v1 = *reinterpret_cast<const bf16x8*>(VB + vrow*128 + ((t2*64 + 32 + hi*16) ^ ((vrow&7)<<4)));
            acc1 = MFMA32(v0, pf0, acc1);
            acc1 = MFMA32(v1, pf1, acc1);
          }
          ls = MFMA32(onesf, pf0, ls);
          ls = MFMA32(onesf, pf1, ls);
          __builtin_amdgcn_s_setprio(0);
        }
      }
    }
    __syncthreads();
    cur ^= 1;
  }
  #undef STAGE

  char* T = lds + w*4096;
  float inv = 1.0f / ls[0];
  #pragma unroll
  for (int i=0; i<8; ++i){
    int d = (2*i & 3) + 8*(2*i >> 2) + 4*hi;
    u32 wv0 = cvtpk(acc0[2*i]*inv, acc0[2*i+1]*inv);
    *reinterpret_cast<u32*>(T + lo*128 + ((d*2) ^ ((lo&7)<<4))) = wv0;
    u32 wv1 = cvtpk(acc1[2*i]*inv, acc1[2*i+1]*inv);
    *reinterpret_cast<u32*>(T + lo*128 + (((d+32)*2) ^ ((lo&7)<<4))) = wv1;
  }
  __syncthreads();
  const int b = bh >> 4, h = bh & 15;
  #pragma unroll
  for (int i=0; i<4; ++i){
    int q = i*8 + (l>>3), slot = l&7;
    bf16x8 v = *reinterpret_cast<const bf16x8*>(T + q*128 + ((slot*16) ^ ((q&7)<<4)));
    int sq = qb*128 + w*32 + q;
    *reinterpret_cast<bf16x8*>(Ow + ((size_t)(b*2048 + sq))*1024 + h*64 + slot*8) = v;
  }
}

// ---------------- GEMM2: attn @ w_outT^T + bias -> NT f32 out ----------------
__global__ __launch_bounds__(256,4) void gemm_out_k(const u16* __restrict__ A, const u16* __restrict__ Bt,
                                                    const float* __restrict__ bias_p, float* __restrict__ out){
  __shared__ __align__(16) char lds[32768];
  f32x4 acc[4][4];
  #pragma unroll
  for (int m=0;m<4;++m){
    #pragma unroll
    for (int n=0;n<4;++n) acc[m][n] = (f32x4){0.f,0.f,0.f,0.f};
  }
  int id = blockIdx.x + 8*blockIdx.y;
  int nid = (id & 7)*64 + (id >> 3);
  int bn = nid % 8, bm = nid / 8;
  gemm_core(A, Bt, bm, bn, lds, acc);
  int tid = threadIdx.x, w = tid >> 6, l = tid & 63;
  int lrow = l & 15, lg = l >> 4;
  int wm = w >> 1, wn = w & 1;
  #pragma unroll
  for (int n=0;n<4;++n){
    int gcol = bn*128 + wn*64 + n*16 + lrow;
    float bias = bias_p[gcol];
    #pragma unroll
    for (int m=0;m<4;++m){
      #pragma unroll
      for (int r=0;r<4;++r){
        int grow = bm*128 + wm*64 + m*16 + lg*4 + r;
        __builtin_nontemporal_store(acc[m][n][r] + bias, out + (size_t)grow*1024 + gcol);
      }
    }
  }
}

extern "C" void kernel_launch(void* const* d_in, const int* in_sizes, int n_in,
                              void* d_out, int out_size, void* d_ws, size_t ws_size,
                              hipStream_t stream){
  (void)in_sizes; (void)n_in; (void)out_size; (void)ws_size;
  const float* x     = (const float*)d_in[0];
  const float* w_qkv = (const float*)d_in[1];
  const float* w_out = (const float*)d_in[2];
  const float* b_out = (const float*)d_in[3];
  float* out = (float*)d_out;
  char* ws = (char*)d_ws;
  u16* xb    = (u16*)(ws + 0);
  u16* wqkvT = (u16*)(ws + 16777216);
  u16* woutT = (u16*)(ws + 23068672);
  u16* qw    = (u16*)(ws + 25165824);
  u16* kw    = (u16*)(ws + 41943040);
  u16* vtw   = (u16*)(ws + 58720256);
  u16* attn  = (u16*)(ws + 75497472);

  prep_k<<<9216, 256, 0, stream>>>(x, xb, w_qkv, wqkvT, w_out, woutT);
  gemm_qkv_k<<<dim3(24,64), 256, 0, stream>>>(xb, wqkvT, qw, kw, vtw);
  attn_k<<<dim3(64,16), 256, 0, stream>>>(qw, kw, vtw, attn);
  gemm_out_k<<<dim3(8,64), 256, 0, stream>>>(attn, woutT, b_out, out);
}

// Round 15
// 167.688 us; speedup vs baseline: 1.2068x; 1.1008x over previous
//
#include <hip/hip_runtime.h>
#include <stdint.h>

typedef unsigned short u16;
typedef uint32_t u32;
typedef __attribute__((ext_vector_type(4))) float f32x4;
typedef __attribute__((ext_vector_type(16))) float f32x16;
typedef __attribute__((ext_vector_type(8))) short bf16x8;
typedef __attribute__((ext_vector_type(4))) u32 u32x4;

#define MFMA16(a,b,c) __builtin_amdgcn_mfma_f32_16x16x32_bf16((a),(b),(c),0,0,0)
#define MFMA32(a,b,c) __builtin_amdgcn_mfma_f32_32x32x16_bf16((a),(b),(c),0,0,0)
#define QSCALE 0.18033688011112042f   /* 0.125 * log2(e) */
#define MASKB  -1803.3688011112042f   /* -10000 * QSCALE */
#define MBASE  -16.0f                 /* fixed softmax base (log2 domain) */

__device__ __forceinline__ u16 f2bf(float f){
  union { float f; uint32_t u; } v; v.f = f;
  uint32_t r = v.u + 0x7fffu + ((v.u >> 16) & 1u);
  return (u16)(r >> 16);
}

__device__ __forceinline__ u32 cvtpk(float lo, float hi){
  u32 r;
  asm volatile("v_cvt_pk_bf16_f32 %0, %1, %2" : "=v"(r) : "v"(lo), "v"(hi));
  return r;
}

__device__ __forceinline__ void plswap(u32 &a, u32 &b){
  auto r = __builtin_amdgcn_permlane32_swap(a, b, false, false);
  union { decltype(r) v; u32 w[2]; } u; u.v = r;
  a = u.w[0]; b = u.w[1];
}

union U4 { u32x4 u; bf16x8 b; };
__device__ __forceinline__ bf16x8 mkfrag(u32 a, u32 b, u32 c, u32 d){
  U4 x; x.u = (u32x4){a,b,c,d}; return x.b;
}

__device__ __forceinline__ void gload16(const void* g, void* l){
  __builtin_amdgcn_global_load_lds(
      (const __attribute__((address_space(1))) void*)g,
      (__attribute__((address_space(3))) void*)l, 16, 0, 0);
}

// ---------------- fused pre-pass: cvt x + transpose w_qkv + transpose w_out ----------------
__global__ __launch_bounds__(256) void prep_k(const float* __restrict__ x, u16* __restrict__ xb,
                                              const float* __restrict__ w_qkv, u16* __restrict__ wqkvT,
                                              const float* __restrict__ w_out, u16* __restrict__ woutT){
  __shared__ float tile[64][65];
  const int id = blockIdx.x, t = threadIdx.x;
  if (id < 8192){
    int i = id*256 + t;
    float4 v = reinterpret_cast<const float4*>(x)[i];
    ushort4 o;
    o.x = f2bf(v.x); o.y = f2bf(v.y); o.z = f2bf(v.z); o.w = f2bf(v.w);
    reinterpret_cast<ushort4*>(xb)[i] = o;
    return;
  }
  const float* in; u16* out; int R, C, bx, by;
  if (id < 8960){ int id2 = id - 8192; in = w_qkv; out = wqkvT; R = 1024; C = 3072; bx = id2 % 48; by = id2 / 48; }
  else          { int id3 = id - 8960; in = w_out; out = woutT; R = 1024; C = 1024; bx = id3 % 16; by = id3 / 16; }
  int c0 = bx*64, r0 = by*64;
  int cc = t & 63, rr = t >> 6;
  #pragma unroll
  for (int i=0;i<16;++i){ int r = rr + i*4; tile[r][cc] = in[(size_t)(r0+r)*C + c0+cc]; }
  __syncthreads();
  #pragma unroll
  for (int i=0;i<16;++i){ int r = rr + i*4; out[(size_t)(c0+r)*R + r0+cc] = f2bf(tile[cc][r]); }
}

// ---------------- GEMM core (R4-proven): 128x128 tile, BK=64, 2-barrier ----------------
__device__ __forceinline__ void gemm_core(const u16* __restrict__ A, const u16* __restrict__ Bt,
                                          int bm, int bn, char* lds, f32x4 (&acc)[4][4]){
  const int K = 1024;
  int tid = threadIdx.x, w = tid >> 6, l = tid & 63;
  int lrow = l & 15, lg = l >> 4;
  int wm = w >> 1, wn = w & 1;
  const u16* aSrc = A + (size_t)(bm*128 + w*32 + (l>>3))*K + (((l&7)^(l>>3))<<3);
  const u16* bSrc = Bt + (size_t)(bn*128 + w*32 + (l>>3))*K + (((l&7)^(l>>3))<<3);
  char* aDst = lds + w*4096;
  char* bDst = lds + 16384 + w*4096;
  for (int kk = 0; kk < 16; ++kk){
    __syncthreads();
    #pragma unroll
    for (int i=0;i<4;++i) gload16(aSrc + (size_t)i*8*K + kk*64, aDst + i*1024);
    #pragma unroll
    for (int i=0;i<4;++i) gload16(bSrc + (size_t)i*8*K + kk*64, bDst + i*1024);
    __syncthreads();
    #pragma unroll
    for (int ks=0; ks<2; ++ks){
      bf16x8 af[4], bfv[4];
      #pragma unroll
      for (int m=0;m<4;++m){
        int row = wm*64 + m*16 + lrow;
        af[m] = *reinterpret_cast<const bf16x8*>(lds + row*128 + (((ks*4+lg)^(row&7))<<4));
      }
      #pragma unroll
      for (int n=0;n<4;++n){
        int row = wn*64 + n*16 + lrow;
        bfv[n] = *reinterpret_cast<const bf16x8*>(lds + 16384 + row*128 + (((ks*4+lg)^(row&7))<<4));
      }
      #pragma unroll
      for (int m=0;m<4;++m){
        #pragma unroll
        for (int n=0;n<4;++n)
          acc[m][n] = MFMA16(af[m], bfv[n], acc[m][n]);
      }
    }
  }
}

// ---------------- GEMM1 (R9-proven): x @ w_qkvT^T -> cached scatter q,k + LDS-transposed vT ----------------
__global__ __launch_bounds__(256,5) void gemm_qkv_k(const u16* __restrict__ A, const u16* __restrict__ Bt,
                                                    u16* __restrict__ qw, u16* __restrict__ kw,
                                                    u16* __restrict__ vtw){
  __shared__ __align__(16) char lds[32768];
  f32x4 acc[4][4];
  #pragma unroll
  for (int m=0;m<4;++m){
    #pragma unroll
    for (int n=0;n<4;++n) acc[m][n] = (f32x4){0.f,0.f,0.f,0.f};
  }
  int id = blockIdx.x + 24*blockIdx.y;  // 0..1535
  int xcd = id & 7, s = id >> 3;        // s: 0..191
  int cb = s / 48, r = s % 48;          // 4 column-passes of 8bm x 6bn
  int bm = xcd*8 + r/6;                 // 0..63
  int bn = cb*6 + r%6;                  // 0..23
  gemm_core(A, Bt, bm, bn, lds, acc);
  int tid = threadIdx.x, w = tid >> 6, l = tid & 63;
  int lrow = l & 15, lg = l >> 4;
  int wm = w >> 1, wn = w & 1;
  const int which = bn >> 3;   // 128-col block lies entirely in one of q/k/v
  if (which < 2){
    // cached stores: L2 write-combines the 2B/lane scatter (NT here = 1.7x write amp, R13)
    #pragma unroll
    for (int n=0;n<4;++n){
      int gcol = bn*128 + wn*64 + n*16 + lrow;
      int inner = gcol & 1023;
      int h = inner >> 6, d = inner & 63;
      #pragma unroll
      for (int m=0;m<4;++m){
        #pragma unroll
        for (int r2=0;r2<4;++r2){
          int grow = bm*128 + wm*64 + m*16 + lg*4 + r2; // b*S + s
          int b = grow >> 11, sq = grow & 2047;
          float v = acc[m][n][r2];
          if (which == 0)
            qw[((size_t)((b*16 + h)*2048 + sq))*64 + d] = f2bf(v * QSCALE);
          else
            kw[((size_t)((b*16 + h)*2048 + sq))*64 + d] = f2bf(v);
        }
      }
    }
  } else {
    // V block: transpose through LDS -> cached 16B stores (NT here = 4x write amp, R14:
    // each instruction deposits only 16B per 64B sector; L2 merges across instructions)
    __syncthreads();
    #pragma unroll
    for (int n=0;n<4;++n){
      int colL = wn*64 + n*16 + lrow;           // local d' 0..127
      int swz = (colL & 7) << 4;
      #pragma unroll
      for (int m=0;m<4;++m){
        int rowL0 = wm*64 + m*16 + lg*4;        // local sq' 4 consecutive
        ushort4 p;
        p.x = f2bf(acc[m][n][0]); p.y = f2bf(acc[m][n][1]);
        p.z = f2bf(acc[m][n][2]); p.w = f2bf(acc[m][n][3]);
        *reinterpret_cast<ushort4*>(lds + colL*256 + ((rowL0*2) ^ swz)) = p;
      }
    }
    __syncthreads();
    const int h0 = bn*2 - 32;
    const int grow0 = bm*128;
    const int b = grow0 >> 11, sq0 = grow0 & 2047;
    const int dp = tid >> 1;
    const int half = (tid & 1) * 128;
    const int h = h0 + (dp >> 6), d = dp & 63;
    const int swz = (dp & 7) << 4;
    u16* dst = vtw + ((size_t)((b*16 + h)*64 + d))*2048 + sq0 + half/2;
    #pragma unroll
    for (int i=0;i<8;++i){
      u32x4 v = *reinterpret_cast<const u32x4*>(lds + dp*256 + ((half + i*16) ^ swz));
      *reinterpret_cast<u32x4*>(dst + i*8) = v;
    }
  }
}

// ---------------- flash attention v5 (R9-proven): fixed-base softmax, l-sum via MFMA ----------------
__global__ __launch_bounds__(256) void attn_k(const u16* __restrict__ Qw, const u16* __restrict__ Kw,
                                              const u16* __restrict__ VTw, u16* __restrict__ Ow){
  __shared__ __align__(16) char lds[32768];
  const int bh = blockIdx.x;
  const int y = blockIdx.y, yk = y >> 2, ya = y & 3;
  const int qb = (yk == 0) ? (15 - ya) : (yk == 1) ? (8 + ya) : (yk == 2) ? (4 + ya) : (3 - ya);
  const int tid = threadIdx.x, w = tid >> 6, l = tid & 63;
  const int lo = l & 31, hi = l >> 5;
  const size_t base = (size_t)bh * (2048*64);
  const int qw0 = qb*128 + w*32;
  const int q_l = qw0 + lo;

  bf16x8 qa[4];
  {
    const u16* qsrc = Qw + base + (size_t)q_l*64 + hi*8;
    #pragma unroll
    for (int ks=0; ks<4; ++ks) qa[ks] = *reinterpret_cast<const bf16x8*>(qsrc + ks*16);
  }

  const u32 ONE2 = 0x3F803F80u;
  const bf16x8 onesf = mkfrag(ONE2, ONE2, ONE2, ONE2);

  const int srow = tid >> 3;
  const int scs  = (tid & 7) ^ (srow & 7);
  const u16* kS = Kw  + base + (size_t)srow*64   + scs*8;
  const u16* vS = VTw + base + (size_t)srow*2048 + scs*8;

  f32x16 acc0 = {0,0,0,0,0,0,0,0,0,0,0,0,0,0,0,0};
  f32x16 acc1 = {0,0,0,0,0,0,0,0,0,0,0,0,0,0,0,0};
  f32x16 ls   = {0,0,0,0,0,0,0,0,0,0,0,0,0,0,0,0};
  const f32x16 minit = {MBASE,MBASE,MBASE,MBASE,MBASE,MBASE,MBASE,MBASE,
                        MBASE,MBASE,MBASE,MBASE,MBASE,MBASE,MBASE,MBASE};

  const int nt = qb*2 + 2;

  #define STAGE(buf, t) do { \
    int kv0_ = (t)*64; \
    gload16(kS + (size_t)kv0_*64,        lds + (buf)*16384 +     0 + w*1024); \
    gload16(kS + (size_t)(kv0_+32)*64,   lds + (buf)*16384 +  4096 + w*1024); \
    gload16(vS + kv0_,                   lds + (buf)*16384 +  8192 + w*1024); \
    gload16(vS + kv0_ + (size_t)32*2048, lds + (buf)*16384 + 12288 + w*1024); \
  } while(0)

  STAGE(0, 0);
  __syncthreads();

  int cur = 0;
  for (int t = 0; t < nt; ++t){
    if (t+1 < nt){
      if (cur) STAGE(0, t+1); else STAGE(1, t+1);
    }
    const int kv0 = t*64;
    const char* KB = lds + cur*16384;
    const char* VB = KB + 8192;
    if (kv0 + 63 <= qw0){
      f32x16 s0 = minit;
      f32x16 s1 = minit;
      __builtin_amdgcn_s_setprio(1);
      #pragma unroll
      for (int ks=0; ks<4; ++ks){
        int kr0 = lo, kr1 = 32 + lo;
        bf16x8 kf0 = *reinterpret_cast<const bf16x8*>(KB + kr0*128 + ((ks*32 + hi*16) ^ ((kr0&7)<<4)));
        bf16x8 kf1 = *reinterpret_cast<const bf16x8*>(KB + kr1*128 + ((ks*32 + hi*16) ^ ((kr1&7)<<4)));
        s0 = MFMA32(kf0, qa[ks], s0);
        s1 = MFMA32(kf1, qa[ks], s1);
      }
      __builtin_amdgcn_s_setprio(0);
      #pragma unroll
      for (int r=0; r<16; ++r) s0[r] = exp2f(s0[r]);
      #pragma unroll
      for (int r=0; r<16; ++r) s1[r] = exp2f(s1[r]);
      u32 wd0 = cvtpk(s0[0],s0[1]),   wd1 = cvtpk(s0[2],s0[3]);
      u32 wd2 = cvtpk(s0[4],s0[5]),   wd3 = cvtpk(s0[6],s0[7]);
      u32 wd4 = cvtpk(s0[8],s0[9]),   wd5 = cvtpk(s0[10],s0[11]);
      u32 wd6 = cvtpk(s0[12],s0[13]), wd7 = cvtpk(s0[14],s0[15]);
      u32 we0 = cvtpk(s1[0],s1[1]),   we1 = cvtpk(s1[2],s1[3]);
      u32 we2 = cvtpk(s1[4],s1[5]),   we3 = cvtpk(s1[6],s1[7]);
      u32 we4 = cvtpk(s1[8],s1[9]),   we5 = cvtpk(s1[10],s1[11]);
      u32 we6 = cvtpk(s1[12],s1[13]), we7 = cvtpk(s1[14],s1[15]);
      plswap(wd0, wd2); plswap(wd1, wd3); plswap(wd4, wd6); plswap(wd5, wd7);
      plswap(we0, we2); plswap(we1, we3); plswap(we4, we6); plswap(we5, we7);
      bf16x8 pf0 = mkfrag(wd0, wd1, wd2, wd3);
      bf16x8 pf1 = mkfrag(wd4, wd5, wd6, wd7);
      bf16x8 pf2 = mkfrag(we0, we1, we2, we3);
      bf16x8 pf3 = mkfrag(we4, we5, we6, we7);
      __builtin_amdgcn_s_setprio(1);
      {
        int vrow = lo;
        bf16x8 v0 = *reinterpret_cast<const bf16x8*>(VB + vrow*128 + ((      hi*16) ^ ((vrow&7)<<4)));
        bf16x8 v1 = *reinterpret_cast<const bf16x8*>(VB + vrow*128 + (( 32 + hi*16) ^ ((vrow&7)<<4)));
        bf16x8 v2 = *reinterpret_cast<const bf16x8*>(VB + vrow*128 + (( 64 + hi*16) ^ ((vrow&7)<<4)));
        bf16x8 v3 = *reinterpret_cast<const bf16x8*>(VB + vrow*128 + (( 96 + hi*16) ^ ((vrow&7)<<4)));
        acc0 = MFMA32(v0, pf0, acc0);
        acc0 = MFMA32(v1, pf1, acc0);
        acc0 = MFMA32(v2, pf2, acc0);
        acc0 = MFMA32(v3, pf3, acc0);
      }
      {
        int vrow = 32 + lo;
        bf16x8 v0 = *reinterpret_cast<const bf16x8*>(VB + vrow*128 + ((      hi*16) ^ ((vrow&7)<<4)));
        bf16x8 v1 = *reinterpret_cast<const bf16x8*>(VB + vrow*128 + (( 32 + hi*16) ^ ((vrow&7)<<4)));
        bf16x8 v2 = *reinterpret_cast<const bf16x8*>(VB + vrow*128 + (( 64 + hi*16) ^ ((vrow&7)<<4)));
        bf16x8 v3 = *reinterpret_cast<const bf16x8*>(VB + vrow*128 + (( 96 + hi*16) ^ ((vrow&7)<<4)));
        acc1 = MFMA32(v0, pf0, acc1);
        acc1 = MFMA32(v1, pf1, acc1);
        acc1 = MFMA32(v2, pf2, acc1);
        acc1 = MFMA32(v3, pf3, acc1);
      }
      ls = MFMA32(onesf, pf0, ls);
      ls = MFMA32(onesf, pf1, ls);
      ls = MFMA32(onesf, pf2, ls);
      ls = MFMA32(onesf, pf3, ls);
      __builtin_amdgcn_s_setprio(0);
    } else if (kv0 < qw0 + 32){
      #pragma unroll
      for (int t2=0; t2<2; ++t2){
        const int kvs0 = kv0 + t2*32;
        if (kvs0 < qw0 + 32){
          f32x16 s = minit;
          __builtin_amdgcn_s_setprio(1);
          #pragma unroll
          for (int ks=0; ks<4; ++ks){
            int krow = t2*32 + lo;
            bf16x8 kf = *reinterpret_cast<const bf16x8*>(KB + krow*128 + ((ks*32 + hi*16) ^ ((krow&7)<<4)));
            s = MFMA32(kf, qa[ks], s);
          }
          __builtin_amdgcn_s_setprio(0);
          if (kvs0 + 31 > qw0){
            #pragma unroll
            for (int r=0; r<16; ++r){
              int kvg = kvs0 + (r&3) + 8*(r>>2) + 4*hi;
              if (kvg > q_l) s[r] += MASKB;
            }
          }
          #pragma unroll
          for (int r=0; r<16; ++r) s[r] = exp2f(s[r]);
          u32 wd0 = cvtpk(s[0], s[1]),   wd1 = cvtpk(s[2], s[3]);
          u32 wd2 = cvtpk(s[4], s[5]),   wd3 = cvtpk(s[6], s[7]);
          u32 wd4 = cvtpk(s[8], s[9]),   wd5 = cvtpk(s[10], s[11]);
          u32 wd6 = cvtpk(s[12], s[13]), wd7 = cvtpk(s[14], s[15]);
          plswap(wd0, wd2); plswap(wd1, wd3);
          plswap(wd4, wd6); plswap(wd5, wd7);
          bf16x8 pf0 = mkfrag(wd0, wd1, wd2, wd3);
          bf16x8 pf1 = mkfrag(wd4, wd5, wd6, wd7);
          __builtin_amdgcn_s_setprio(1);
          {
            int vrow = lo;
            bf16x8 v0 = *reinterpret_cast<const bf16x8*>(VB + vrow*128 + ((t2*64 +      hi*16) ^ ((vrow&7)<<4)));
            bf16x8 v1 = *reinterpret_cast<const bf16x8*>(VB + vrow*128 + ((t2*64 + 32 + hi*16) ^ ((vrow&7)<<4)));
            acc0 = MFMA32(v0, pf0, acc0);
            acc0 = MFMA32(v1, pf1, acc0);
          }
          {
            int vrow = 32 + lo;
            bf16x8 v0 = *reinterpret_cast<const bf16x8*>(VB + vrow*128 + ((t2*64 +      hi*16) ^ ((vrow&7)<<4)));
            bf16x8 v1 = *reinterpret_cast<const bf16x8*>(VB + vrow*128 + ((t2*64 + 32 + hi*16) ^ ((vrow&7)<<4)));
            acc1 = MFMA32(v0, pf0, acc1);
            acc1 = MFMA32(v1, pf1, acc1);
          }
          ls = MFMA32(onesf, pf0, ls);
          ls = MFMA32(onesf, pf1, ls);
          __builtin_amdgcn_s_setprio(0);
        }
      }
    }
    __syncthreads();
    cur ^= 1;
  }
  #undef STAGE

  char* T = lds + w*4096;
  float inv = 1.0f / ls[0];
  #pragma unroll
  for (int i=0; i<8; ++i){
    int d = (2*i & 3) + 8*(2*i >> 2) + 4*hi;
    u32 wv0 = cvtpk(acc0[2*i]*inv, acc0[2*i+1]*inv);
    *reinterpret_cast<u32*>(T + lo*128 + ((d*2) ^ ((lo&7)<<4))) = wv0;
    u32 wv1 = cvtpk(acc1[2*i]*inv, acc1[2*i+1]*inv);
    *reinterpret_cast<u32*>(T + lo*128 + (((d+32)*2) ^ ((lo&7)<<4))) = wv1;
  }
  __syncthreads();
  const int b = bh >> 4, h = bh & 15;
  #pragma unroll
  for (int i=0; i<4; ++i){
    int q = i*8 + (l>>3), slot = l&7;
    bf16x8 v = *reinterpret_cast<const bf16x8*>(T + q*128 + ((slot*16) ^ ((q&7)<<4)));
    int sq = qb*128 + w*32 + q;
    *reinterpret_cast<bf16x8*>(Ow + ((size_t)(b*2048 + sq))*1024 + h*64 + slot*8) = v;
  }
}

// ---------------- GEMM2: attn @ w_outT^T + bias -> NT f32 out (full-sector per instr) ----------------
__global__ __launch_bounds__(256,4) void gemm_out_k(const u16* __restrict__ A, const u16* __restrict__ Bt,
                                                    const float* __restrict__ bias_p, float* __restrict__ out){
  __shared__ __align__(16) char lds[32768];
  f32x4 acc[4][4];
  #pragma unroll
  for (int m=0;m<4;++m){
    #pragma unroll
    for (int n=0;n<4;++n) acc[m][n] = (f32x4){0.f,0.f,0.f,0.f};
  }
  int id = blockIdx.x + 8*blockIdx.y;
  int nid = (id & 7)*64 + (id >> 3);
  int bn = nid % 8, bm = nid / 8;
  gemm_core(A, Bt, bm, bn, lds, acc);
  int tid = threadIdx.x, w = tid >> 6, l = tid & 63;
  int lrow = l & 15, lg = l >> 4;
  int wm = w >> 1, wn = w & 1;
  #pragma unroll
  for (int n=0;n<4;++n){
    int gcol = bn*128 + wn*64 + n*16 + lrow;
    float bias = bias_p[gcol];
    #pragma unroll
    for (int m=0;m<4;++m){
      #pragma unroll
      for (int r=0;r<4;++r){
        int grow = bm*128 + wm*64 + m*16 + lg*4 + r;
        __builtin_nontemporal_store(acc[m][n][r] + bias, out + (size_t)grow*1024 + gcol);
      }
    }
  }
}

extern "C" void kernel_launch(void* const* d_in, const int* in_sizes, int n_in,
                              void* d_out, int out_size, void* d_ws, size_t ws_size,
                              hipStream_t stream){
  (void)in_sizes; (void)n_in; (void)out_size; (void)ws_size;
  const float* x     = (const float*)d_in[0];
  const float* w_qkv = (const float*)d_in[1];
  const float* w_out = (const float*)d_in[2];
  const float* b_out = (const float*)d_in[3];
  float* out = (float*)d_out;
  char* ws = (char*)d_ws;
  u16* xb    = (u16*)(ws + 0);
  u16* wqkvT = (u16*)(ws + 16777216);
  u16* woutT = (u16*)(ws + 23068672);
  u16* qw    = (u16*)(ws + 25165824);
  u16* kw    = (u16*)(ws + 41943040);
  u16* vtw   = (u16*)(ws + 58720256);
  u16* attn  = (u16*)(ws + 75497472);

  prep_k<<<9216, 256, 0, stream>>>(x, xb, w_qkv, wqkvT, w_out, woutT);
  gemm_qkv_k<<<dim3(24,64), 256, 0, stream>>>(xb, wqkvT, qw, kw, vtw);
  attn_k<<<dim3(64,16), 256, 0, stream>>>(qw, kw, vtw, attn);
  gemm_out_k<<<dim3(8,64), 256, 0, stream>>>(attn, woutT, b_out, out);
}